// Round 1
// baseline (563.106 us; speedup 1.0000x reference)
//
#include <hip/hip_runtime.h>

#define NTOK 98
#define DIMC 128
#define HD 32

typedef __attribute__((ext_vector_type(8))) short s8v;
typedef __attribute__((ext_vector_type(4))) float f4v;

__device__ __forceinline__ ushort f2bf(float f) {
  union { float fv; unsigned u; } c; c.fv = f;
  unsigned r = c.u + 0x7fffu + ((c.u >> 16) & 1u);
  return (ushort)(r >> 16);
}
__device__ __forceinline__ unsigned pack2(float a, float b) {
  return (unsigned)f2bf(a) | ((unsigned)f2bf(b) << 16);
}

// Pre-gather relative-position bias into [4][98][98] fp32 and convert weights to bf16.
__global__ void setup_kernel(const float* __restrict__ rpb, const int* __restrict__ rel_idx,
                             const float* __restrict__ qkv_w, const float* __restrict__ proj_w,
                             float* __restrict__ bias_pre, ushort* __restrict__ qkv_wb,
                             ushort* __restrict__ proj_wb) {
  int tid = blockIdx.x * blockDim.x + threadIdx.x;
  int stride = gridDim.x * blockDim.x;
  for (int idx = tid; idx < 4 * NTOK * NTOK; idx += stride) {
    int h = idx / (NTOK * NTOK);
    int ij = idx % (NTOK * NTOK);
    bias_pre[idx] = rpb[rel_idx[ij] * 4 + h];
  }
  for (int idx = tid; idx < 384 * DIMC; idx += stride) qkv_wb[idx] = f2bf(qkv_w[idx]);
  for (int idx = tid; idx < DIMC * DIMC; idx += stride) proj_wb[idx] = f2bf(proj_w[idx]);
}

// One block per batch window b. 8 waves: waves (2h,2h+1) own head h.
// LDS map (ushort units):
//   q   [4][112][32]   @ 0       (aliased by ao [112][128] in proj phase)
//   k   [4][112][32]   @ 14336
//   vT  [4][32][128]   @ 28672
//   P   [8][16][128]   @ 45056   (aliased by x-stage [98][128] during QKV)
// total 61440 ushorts = 120 KiB
__global__ __launch_bounds__(512, 2)
void fused_wattn(const float* __restrict__ x, const float* __restrict__ maskg,
                 const float* __restrict__ qkv_b, const float* __restrict__ proj_b,
                 const float* __restrict__ bias_pre,
                 const ushort* __restrict__ qkv_wb, const ushort* __restrict__ proj_wb,
                 float* __restrict__ out) {
  __shared__ ushort smem[61440];
  const int b = blockIdx.x;
  const int tid = threadIdx.x;
  const int wave = tid >> 6;
  const int lane = tid & 63;
  const int l16 = lane & 15;
  const int lg = lane >> 4;
  const int head = wave >> 1;
  const int hf = wave & 1;

  ushort* q_lds = smem;                       // [4][112][32]
  ushort* k_lds = smem + 4 * 112 * HD;        // [4][112][32]
  ushort* vT_lds = smem + 8 * 112 * HD;       // [4][32][128]
  ushort* P_base = smem + 8 * 112 * HD + 4 * HD * DIMC;  // [8][16][128]
  char* xc = reinterpret_cast<char*>(P_base);             // x-stage alias (bytes)
  char* Pc = reinterpret_cast<char*>(P_base + wave * 16 * DIMC);

  // zero q/k/vT (pad rows/cols must be 0): 45056 ushorts = 5632 uint4
  {
    uint4* p = reinterpret_cast<uint4*>(smem);
    uint4 z{0, 0, 0, 0};
    for (int i = tid; i < 5632; i += 512) p[i] = z;
  }
  // stage x -> bf16 LDS with XOR swizzle (byte ^= (row&7)<<4)
  {
    const float4* x4 = reinterpret_cast<const float4*>(x + (size_t)b * NTOK * DIMC);
    for (int i = tid; i < 3136; i += 512) {
      float4 f = x4[i];
      uint2 u;
      u.x = pack2(f.x, f.y);
      u.y = pack2(f.z, f.w);
      int row = i >> 5;
      int off = (i * 8) ^ ((row & 7) << 4);
      *reinterpret_cast<uint2*>(xc + off) = u;
    }
  }
  __syncthreads();

  // ---------------- QKV GEMM ----------------
  // otile o covers output channels [16o,16o+16) of the 384-wide qkv output.
  // wave 2h: q-tiles {2h,2h+1} + k-tile {8+2h};  wave 2h+1: {9+2h, 16+2h, 17+2h}
  int otiles[3];
  if (hf == 0) { otiles[0] = 2 * head; otiles[1] = 2 * head + 1; otiles[2] = 8 + 2 * head; }
  else         { otiles[0] = 9 + 2 * head; otiles[1] = 16 + 2 * head; otiles[2] = 17 + 2 * head; }

  s8v wfrag[3][4];
  float bofs[3];
#pragma unroll
  for (int t = 0; t < 3; ++t) {
    int o = otiles[t];
#pragma unroll
    for (int kc = 0; kc < 4; ++kc)
      wfrag[t][kc] = *reinterpret_cast<const s8v*>(&qkv_wb[(o * 16 + l16) * DIMC + kc * 32 + lg * 8]);
    bofs[t] = qkv_b[o * 16 + l16];
  }

#pragma unroll
  for (int mt = 0; mt < 7; ++mt) {
    int row = mt * 16 + l16;
    s8v afrag[4];
    if (row < NTOK) {
#pragma unroll
      for (int kc = 0; kc < 4; ++kc) {
        int off = (row * 256 + kc * 64 + lg * 16) ^ ((row & 7) << 4);
        afrag[kc] = *reinterpret_cast<const s8v*>(xc + off);
      }
    } else {
      s8v z = {0, 0, 0, 0, 0, 0, 0, 0};
#pragma unroll
      for (int kc = 0; kc < 4; ++kc) afrag[kc] = z;
    }
#pragma unroll
    for (int t = 0; t < 3; ++t) {
      f4v acc = {0.f, 0.f, 0.f, 0.f};
#pragma unroll
      for (int kc = 0; kc < 4; ++kc)
        acc = __builtin_amdgcn_mfma_f32_16x16x32_bf16(afrag[kc], wfrag[t][kc], acc, 0, 0, 0);
      int o = otiles[t];
      int chan = o * 16 + l16;
      int d = chan & 31;
#pragma unroll
      for (int r = 0; r < 4; ++r) {
        int n = mt * 16 + lg * 4 + r;
        if (n < NTOK) {
          ushort uv = f2bf(acc[r] + bofs[t]);
          if (o < 8)       q_lds[(head * 112 + n) * HD + d] = uv;
          else if (o < 16) k_lds[(head * 112 + n) * HD + d] = uv;
          else             vT_lds[(head * HD + d) * DIMC + n] = uv;  // transposed for PV B-op
        }
      }
    }
  }
  __syncthreads();

  // zero this wave's P pad cols 112..127 (x-stage alias is dead now)
  for (int idx = lane; idx < 256; idx += 64) {
    int rw = idx >> 4, cl = 112 + (idx & 15);
    int off = (rw * 256 + cl * 2) ^ ((rw & 7) << 4);
    *reinterpret_cast<ushort*>(Pc + off) = 0;
  }

  // ---------------- attention ----------------
  s8v kfrag[7];
#pragma unroll
  for (int jt = 0; jt < 7; ++jt)
    kfrag[jt] = *reinterpret_cast<const s8v*>(&k_lds[(head * 112 + jt * 16 + l16) * HD + lg * 8]);
  s8v vfrag[2][4];
#pragma unroll
  for (int dt = 0; dt < 2; ++dt)
#pragma unroll
    for (int kc = 0; kc < 4; ++kc)
      vfrag[dt][kc] = *reinterpret_cast<const s8v*>(&vT_lds[(head * HD + dt * 16 + l16) * DIMC + kc * 32 + lg * 8]);

  const float* maskp = maskg + (size_t)(b & 63) * NTOK * NTOK;
  const float* biasp = bias_pre + (size_t)head * NTOK * NTOK;
  const int it0 = hf * 3;  // halves: itiles {0..3} and {3..6}; itile 3 duplicated (benign)
  f4v oacc[4][2];
  const float SC = 0.17677669529663687f;  // 32^-0.5

#pragma unroll
  for (int ii = 0; ii < 4; ++ii) {
    const int it = it0 + ii;
    s8v qfrag = *reinterpret_cast<const s8v*>(&q_lds[(head * 112 + it * 16 + l16) * HD + lg * 8]);
    f4v zz = {0.f, 0.f, 0.f, 0.f};
    f4v S[7];
#pragma unroll
    for (int jt = 0; jt < 7; ++jt)
      S[jt] = __builtin_amdgcn_mfma_f32_16x16x32_bf16(qfrag, kfrag[jt], zz, 0, 0, 0);
    // scale + bias + mask in fp32; invalid rows/cols -> -1e30
#pragma unroll
    for (int r = 0; r < 4; ++r) {
      int i = it * 16 + lg * 4 + r;
      bool iv = (i < NTOK);
#pragma unroll
      for (int jt = 0; jt < 7; ++jt) {
        int j = jt * 16 + l16;
        if (iv && j < NTOK)
          S[jt][r] = S[jt][r] * SC + biasp[i * NTOK + j] + maskp[i * NTOK + j];
        else
          S[jt][r] = -1e30f;
      }
    }
    // wave-parallel softmax: row i lives in lane-group lg=(i%16)/4, reg r=i%4; j across l16 & jt
    float srow[4];
#pragma unroll
    for (int r = 0; r < 4; ++r) {
      float m = S[0][r];
#pragma unroll
      for (int jt = 1; jt < 7; ++jt) m = fmaxf(m, S[jt][r]);
      m = fmaxf(m, __shfl_xor(m, 1));
      m = fmaxf(m, __shfl_xor(m, 2));
      m = fmaxf(m, __shfl_xor(m, 4));
      m = fmaxf(m, __shfl_xor(m, 8));
      float s = 0.f;
#pragma unroll
      for (int jt = 0; jt < 7; ++jt) {
        float p = exp2f((S[jt][r] - m) * 1.4426950408889634f);
        S[jt][r] = p;
        s += p;
      }
      s += __shfl_xor(s, 1);
      s += __shfl_xor(s, 2);
      s += __shfl_xor(s, 4);
      s += __shfl_xor(s, 8);
      srow[r] = s;
    }
    // P -> LDS bf16 (swizzled); pad cols j>=98 get exp(-1e30-m)=0 automatically
#pragma unroll
    for (int r = 0; r < 4; ++r) {
      int rw = lg * 4 + r;
#pragma unroll
      for (int jt = 0; jt < 7; ++jt) {
        int off = (rw * 256 + (jt * 16 + l16) * 2) ^ ((rw & 7) << 4);
        *reinterpret_cast<ushort*>(Pc + off) = f2bf(S[jt][r]);
      }
    }
    asm volatile("s_waitcnt lgkmcnt(0)" ::: "memory");  // cross-lane P write->read, same wave
    // PV
    f4v o0 = zz, o1 = zz;
#pragma unroll
    for (int kc = 0; kc < 4; ++kc) {
      int off = (l16 * 256 + kc * 64 + lg * 16) ^ ((l16 & 7) << 4);
      s8v pf = *reinterpret_cast<const s8v*>(Pc + off);
      o0 = __builtin_amdgcn_mfma_f32_16x16x32_bf16(pf, vfrag[0][kc], o0, 0, 0, 0);
      o1 = __builtin_amdgcn_mfma_f32_16x16x32_bf16(pf, vfrag[1][kc], o1, 0, 0, 0);
    }
#pragma unroll
    for (int r = 0; r < 4; ++r) {
      float inv = 1.0f / srow[r];
      o0[r] *= inv;
      o1[r] *= inv;
    }
    oacc[ii][0] = o0;
    oacc[ii][1] = o1;
  }
  __syncthreads();  // all q/k reads done -> safe to alias ao over q region

  // ---------------- attn-out -> LDS (bf16, swizzled), then proj ----------------
  char* aoc = reinterpret_cast<char*>(smem);  // ao [112][128] aliases q region
#pragma unroll
  for (int ii = 0; ii < 4; ++ii) {
    int it = it0 + ii;
#pragma unroll
    for (int r = 0; r < 4; ++r) {
      int n = it * 16 + lg * 4 + r;
      if (n < NTOK) {
        int c0 = head * 32 + l16;
        int off0 = (n * 256 + c0 * 2) ^ ((n & 7) << 4);
        *reinterpret_cast<ushort*>(aoc + off0) = f2bf(oacc[ii][0][r]);
        int c1 = head * 32 + 16 + l16;
        int off1 = (n * 256 + c1 * 2) ^ ((n & 7) << 4);
        *reinterpret_cast<ushort*>(aoc + off1) = f2bf(oacc[ii][1][r]);
      }
    }
  }
  __syncthreads();

  // proj: wave w owns output-channel tile [16w,16w+16)
  s8v pwf[4];
#pragma unroll
  for (int kc = 0; kc < 4; ++kc)
    pwf[kc] = *reinterpret_cast<const s8v*>(&proj_wb[(wave * 16 + l16) * DIMC + kc * 32 + lg * 8]);
  float pb = proj_b[wave * 16 + l16];
  float* outb = out + (size_t)b * NTOK * DIMC;
#pragma unroll
  for (int mt = 0; mt < 7; ++mt) {
    f4v acc = {0.f, 0.f, 0.f, 0.f};
    int row = mt * 16 + l16;
#pragma unroll
    for (int kc = 0; kc < 4; ++kc) {
      int off = (row * 256 + kc * 64 + lg * 16) ^ ((row & 7) << 4);
      s8v af = *reinterpret_cast<const s8v*>(aoc + off);
      acc = __builtin_amdgcn_mfma_f32_16x16x32_bf16(af, pwf[kc], acc, 0, 0, 0);
    }
#pragma unroll
    for (int r = 0; r < 4; ++r) {
      int n = mt * 16 + lg * 4 + r;
      if (n < NTOK) outb[n * DIMC + wave * 16 + l16] = acc[r] + pb;
    }
  }
}

extern "C" void kernel_launch(void* const* d_in, const int* in_sizes, int n_in,
                              void* d_out, int out_size, void* d_ws, size_t ws_size,
                              hipStream_t stream) {
  const float* x = (const float*)d_in[0];
  const float* mask = (const float*)d_in[1];
  const float* rpb = (const float*)d_in[2];
  const float* qkv_w = (const float*)d_in[3];
  const float* qkv_b = (const float*)d_in[4];
  const float* proj_w = (const float*)d_in[5];
  const float* proj_b = (const float*)d_in[6];
  const int* rel_idx = (const int*)d_in[7];

  float* bias_pre = (float*)d_ws;                                    // 4*98*98*4   = 153664 B
  ushort* qkv_wb = (ushort*)((char*)d_ws + 153664);                  // 384*128*2   =  98304 B
  ushort* proj_wb = (ushort*)((char*)d_ws + 153664 + 98304);         // 128*128*2   =  32768 B

  setup_kernel<<<dim3(64), dim3(256), 0, stream>>>(rpb, rel_idx, qkv_w, proj_w,
                                                   bias_pre, qkv_wb, proj_wb);
  fused_wattn<<<dim3(4096), dim3(512), 0, stream>>>(x, mask, qkv_b, proj_b, bias_pre,
                                                    qkv_wb, proj_wb, (float*)d_out);
}